// Round 2
// baseline (155.207 us; speedup 1.0000x reference)
//
#include <hip/hip_runtime.h>

// DepthwiseTemporalConv: I[n,c,t] = x_flat[n*16384 + c*64 + t], n in [0,4096), c in [0,256), t in [0,64)
// Y[n,c,t] = sum_{k=0}^{63-t} I[n,c,t+k] * W[c,k]
// out_flat[(n>>10)*16777216 + c*65536 + t*1024 + (n&1023)] = Y[n,c,t]
//
// R2: no LDS, no barrier. Each thread direct-loads its contiguous 256B row
// (16x global_load_dwordx4, stride-16KB across lanes; every line fully used ->
// HBM traffic stays 1.0x). Weights via readfirstlane-uniform pointer so the
// compiler can scalarize to s_load (wave-uniform c). Occupancy now VGPR-bound
// instead of LDS-bound (was 2 blocks/CU = 20%).

constexpr int Cc = 256;
constexpr int Tt = 64;
constexpr int Kk = 64;
constexpr int CT = Cc * Tt;   // 16384

__global__ __launch_bounds__(256, 3)
void DepthwiseTemporalConv_24962349924982_kernel(const float* __restrict__ x,
                                                 const float* __restrict__ w,
                                                 float* __restrict__ out) {
    const int tid  = threadIdx.x;
    const int lane = tid & 63;
    const int wv   = tid >> 6;

    const int n_tile = blockIdx.x & 63;   // 64 n-tiles
    const int c_tile = blockIdx.x >> 6;   // 64 c-tiles
    const int n  = n_tile * 64 + lane;
    const int cv = c_tile * 4 + wv;

    // ---- weights: wave-uniform address (readfirstlane) -> scalarizable loads
    const int cu = __builtin_amdgcn_readfirstlane(cv);
    const float* __restrict__ wp = w + (size_t)cu * Kk;
    float wr[Kk];
    #pragma unroll
    for (int m = 0; m < 16; ++m) {
        const float4 v = *(const float4*)(wp + 4 * m);
        wr[4*m+0] = v.x; wr[4*m+1] = v.y; wr[4*m+2] = v.z; wr[4*m+3] = v.w;
    }

    // ---- this thread's row: 64 contiguous floats, 16 dwordx4 loads.
    // Issue high-m first so descending-t compute can start on the oldest loads.
    float xr[Tt];
    const float* __restrict__ rowp = x + (size_t)n * CT + (size_t)cu * Tt;
    #pragma unroll
    for (int m = 15; m >= 0; --m) {
        const float4 v = *(const float4*)(rowp + 4 * m);
        xr[4*m+0] = v.x; xr[4*m+1] = v.y; xr[4*m+2] = v.z; xr[4*m+3] = v.w;
    }

    // ---- triangular suffix correlation, fully unrolled (static reg indices),
    // 2 accumulator chains. Descending t: t=63 needs only xr[63].
    // Stores wave-coalesced: lane -> consecutive n within (d,c,t) plane.
    float* __restrict__ obase = out + (size_t)(n >> 10) * (Cc * Tt * 1024)
                                    + (size_t)cv * (Tt * 1024) + (n & 1023);
    #pragma unroll
    for (int t = Tt - 1; t >= 0; --t) {
        const int len = Tt - t;
        float a0 = 0.f, a1 = 0.f;
        #pragma unroll
        for (int k = 0; k + 1 < len; k += 2) {
            a0 = fmaf(xr[t + k],     wr[k],     a0);
            a1 = fmaf(xr[t + k + 1], wr[k + 1], a1);
        }
        if (len & 1) a0 = fmaf(xr[Tt - 1], wr[len - 1], a0);
        obase[(size_t)t * 1024] = a0 + a1;
    }
}

extern "C" void kernel_launch(void* const* d_in, const int* in_sizes, int n_in,
                              void* d_out, int out_size, void* d_ws, size_t ws_size,
                              hipStream_t stream) {
    const float* x = (const float*)d_in[0];
    const float* w = (const float*)d_in[1];
    float* out = (float*)d_out;
    DepthwiseTemporalConv_24962349924982_kernel<<<dim3(4096), dim3(256), 0, stream>>>(x, w, out);
}

// Round 3
// 152.615 us; speedup vs baseline: 1.0170x; 1.0170x over previous
//
#include <hip/hip_runtime.h>

// DepthwiseTemporalConv: I[n,c,t] = x_flat[n*16384 + c*64 + t], n in [0,4096), c in [0,256), t in [0,64)
// Y[n,c,t] = sum_{k=0}^{63-t} I[n,c,t+k] * W[c,k]
// out_flat[(n>>10)*16777216 + c*65536 + t*1024 + (n&1023)] = Y[n,c,t]
//
// R3: streaming-j formulation. acc[t] += x[j]*w[j-t] for t<=j. Accumulators are
// RMW state -> compiler cannot rematerialize them (R2 failure mode: xr[64] was
// shed to VGPR=40 and global loads were replayed inside the triangular loop).
// Each input float is loaded exactly once. No LDS, no barrier. Weights
// wave-uniform -> SGPRs.

constexpr int Cc = 256;
constexpr int Tt = 64;
constexpr int Kk = 64;
constexpr int CT = Cc * Tt;   // 16384

__global__ __launch_bounds__(256, 3)
void DepthwiseTemporalConv_24962349924982_kernel(const float* __restrict__ x,
                                                 const float* __restrict__ w,
                                                 float* __restrict__ out) {
    const int tid  = threadIdx.x;
    const int lane = tid & 63;
    const int wv   = tid >> 6;

    const int n_tile = blockIdx.x & 63;   // 64 n-tiles
    const int c_tile = blockIdx.x >> 6;   // 64 c-tiles
    const int n  = n_tile * 64 + lane;
    const int cv = c_tile * 4 + wv;

    // ---- weights: wave-uniform address -> scalar loads into SGPRs
    const int cu = __builtin_amdgcn_readfirstlane(cv);
    const float* __restrict__ wp = w + (size_t)cu * Kk;
    float wr[Kk];
    #pragma unroll
    for (int m = 0; m < 16; ++m) {
        const float4 v = *(const float4*)(wp + 4 * m);
        wr[4*m+0] = v.x; wr[4*m+1] = v.y; wr[4*m+2] = v.z; wr[4*m+3] = v.w;
    }

    // ---- 64 accumulators (one per output t) — live RMW state, never shed
    float acc[Tt];
    #pragma unroll
    for (int t = 0; t < Tt; ++t) acc[t] = 0.f;

    // ---- stream this thread's contiguous 256B row, one float4 at a time.
    // Element j contributes to acc[t] for all t <= j with weight w[j-t].
    const float4* __restrict__ rp =
        (const float4*)(x + (size_t)n * CT + (size_t)cu * Tt);
    #pragma unroll
    for (int m = 0; m < 16; ++m) {
        const float4 v = rp[m];
        const float e[4] = {v.x, v.y, v.z, v.w};
        #pragma unroll
        for (int q = 0; q < 4; ++q) {
            const int j = 4 * m + q;
            const float xv = e[q];
            #pragma unroll
            for (int t = 0; t <= j; ++t)
                acc[t] = fmaf(xv, wr[j - t], acc[t]);
        }
    }

    // ---- store: wave-coalesced (lane -> consecutive n within (d,c,t) plane)
    float* __restrict__ obase = out + (size_t)(n >> 10) * (Cc * Tt * 1024)
                                    + (size_t)cv * (Tt * 1024) + (n & 1023);
    #pragma unroll
    for (int t = 0; t < Tt; ++t)
        obase[(size_t)t * 1024] = acc[t];
}

extern "C" void kernel_launch(void* const* d_in, const int* in_sizes, int n_in,
                              void* d_out, int out_size, void* d_ws, size_t ws_size,
                              hipStream_t stream) {
    const float* x = (const float*)d_in[0];
    const float* w = (const float*)d_in[1];
    float* out = (float*)d_out;
    DepthwiseTemporalConv_24962349924982_kernel<<<dim3(4096), dim3(256), 0, stream>>>(x, w, out);
}